// Round 7
// baseline (28.607 us; speedup 1.0000x reference)
//
#include <hip/hip_runtime.h>
#include <math.h>

#define D 256
#define NUF 127.0f
#define C_MAX 128
#define TN 16384
#define T0F (-4.0f)
#define T1F (16.75f)
#define DTF ((T1F - T0F) / (float)(TN - 1))
#define INVDTF ((float)(TN - 1) / (T1F - T0F))
#define LN2F 0.69314718056f
#define RSU 44.3614195558365f  // ln(2^64)

typedef __attribute__((ext_vector_type(8))) short bf16x8;
typedef __attribute__((ext_vector_type(4))) float f32x4;

// float -> bf16 bits, round-to-nearest-even
__device__ __forceinline__ unsigned short f2bf(float f) {
  unsigned u = __float_as_uint(f);
  u += 0x7FFFu + ((u >> 16) & 1u);
  return (unsigned short)(u >> 16);
}

// Miller downward recurrence (i = 254..1), linear space, 2^-64 rescale every
// P steps. Returns log(p_127/p_0) — identical truncation to the reference.
template<int P>
__device__ __forceinline__ float lratio1(float x) {
  float rx = 1.0f / fmaxf(x, 1e-10f);
  float a = 2.0f * rx;
  float cc = 508.0f * rx;  // 2i/x at i=254
  float p = 1.0f, q = 0.0f, k = 0.0f;
  #pragma unroll
  for (int s = 0; s < 127; ++s) {  // i = 254..128; last step yields p_127
    float tn = fmaf(cc, p, q);
    cc -= a; q = p; p = tn;
    if ((s % P) == P - 1 || s == 126) {
      bool b = p > 0x1p64f;
      float sc = b ? 0x1p-64f : 1.0f;
      p *= sc; q *= sc; k += b ? 1.0f : 0.0f;
    }
  }
  float pn = p, kn = k;
  #pragma unroll
  for (int s = 0; s < 127; ++s) {  // i = 127..1
    float tn = fmaf(cc, p, q);
    cc -= a; q = p; p = tn;
    if ((s % P) == P - 1) {
      bool b = p > 0x1p64f;
      float sc = b ? 0x1p-64f : 1.0f;
      p *= sc; q *= sc; k += b ? 1.0f : 0.0f;
    }
  }
  return logf(pn) - logf(p) + (kn - k) * RSU;
}

// log(i0e(x)) via A&S 9.8.1 / 9.8.2 (|err| < 2e-7); t2 = log2(x)
__device__ __forceinline__ float li0e_f(float x, float t2) {
  if (x >= 3.75f) {
    float t = 3.75f / x;
    float P = 0.39894228f + t*(0.01328592f + t*(0.00225319f + t*(-0.00157565f +
              t*(0.00916281f + t*(-0.02057706f + t*(0.02635537f + t*(-0.01647633f +
              t*0.00392377f)))))));
    return logf(P) - 0.5f * LN2F * t2;
  } else {
    float u = x * (1.0f / 3.75f); u *= u;
    float P = 1.0f + u*(3.5156229f + u*(3.0899424f + u*(1.2067492f +
              u*(0.2659732f + u*(0.0360768f + u*0.0045813f)))));
    return logf(P) - x;
  }
}

// logit (without -logc) from s = x^2, table-interpolated Bessel ratio
__device__ __forceinline__ float logit_from(float s, const float* __restrict__ ltab) {
  float x = sqrtf(fmaxf(s, 1e-20f));
  float t2 = log2f(x);
  float fi = fminf(fmaxf((t2 - T0F) * INVDTF, 0.0f), (float)(TN - 1) - 0.001f);
  int i0 = (int)fi;
  float fr = fi - (float)i0;
  float l0 = ltab[i0], l1 = ltab[i0 + 1];
  float lr = fmaf(l1 - l0, fr, l0);
  return li0e_f(x, t2) + lr + x - NUF * (LN2F * t2);
}

// blocks [0,C): per-class stats -> Bg (bf16(2*kappa*mu), [n][k] pre-swizzled),
//               kap2, logc. blocks [C, C+32): lr table; block C zero-pads and
//               resets the k_dot completion counter.
__global__ __launch_bounds__(512) void k_prep(
    const float* __restrict__ F, const float* __restrict__ Ave,
    const float* __restrict__ Amount, const int* __restrict__ labels,
    int N, int C, unsigned short* __restrict__ Bg, float* __restrict__ kap2,
    float* __restrict__ logc, float* __restrict__ ltab,
    unsigned* __restrict__ counter) {
  const int t = threadIdx.x;
  const int bid = blockIdx.x;
  if (bid >= C) {
    int i = (bid - C) * 512 + t;
    if (i < TN) ltab[i] = lratio1<4>(exp2f(T0F + DTF * (float)i));
    if (bid == C) {
      if (t == 0)
        __hip_atomic_store(counter, 0u, __ATOMIC_RELAXED, __HIP_MEMORY_SCOPE_AGENT);
      if (C < C_MAX) {
        uint4 z = make_uint4(0u, 0u, 0u, 0u);
        uint4* B4 = (uint4*)Bg;  // 32 uint4 per 512-byte class row
        for (int j = t; j < (C_MAX - C) * 32; j += 512) B4[C * 32 + j] = z;
        for (int j = t; j < C_MAX - C; j += 512) { kap2[C + j] = 0.0f; logc[C + j] = 0.0f; }
      }
    }
    return;
  }
  const int c = bid;
  const int lane = t & 63, w = t >> 6;
  __shared__ int list[4096];
  __shared__ int wcnt[8];
  __shared__ float red[512];

  // parallel ballot-compaction of matching row indices (deterministic order)
  int total = 0;
  for (int base = 0; base < N; base += 512) {
    int row = base + t;
    bool m = (row < N) && (labels[row] == c);
    unsigned long long mask = __ballot(m);
    if (lane == 0) wcnt[w] = __popcll(mask);
    int before = __popcll(mask & ((1ULL << lane) - 1ULL));
    __syncthreads();
    int woff = total;
    #pragma unroll
    for (int i = 0; i < 8; ++i) { int v = wcnt[i]; if (i < w) woff += v; total += v; }
    if (m) list[woff + before] = row;
    __syncthreads();
  }

  // two halves accumulate alternating list entries; 8 loads in flight each
  const int d = t & 255, half = t >> 8;
  float acc = 0.0f;
  {
    int k = half;
    for (; k + 14 < total; k += 16) {
      int r0 = list[k],      r1 = list[k + 2],  r2 = list[k + 4],  r3 = list[k + 6];
      int r4 = list[k + 8],  r5 = list[k + 10], r6 = list[k + 12], r7 = list[k + 14];
      float v0 = F[(size_t)r0 * D + d], v1 = F[(size_t)r1 * D + d];
      float v2 = F[(size_t)r2 * D + d], v3 = F[(size_t)r3 * D + d];
      float v4 = F[(size_t)r4 * D + d], v5 = F[(size_t)r5 * D + d];
      float v6 = F[(size_t)r6 * D + d], v7 = F[(size_t)r7 * D + d];
      acc += v0; acc += v1; acc += v2; acc += v3;
      acc += v4; acc += v5; acc += v6; acc += v7;
    }
    for (; k < total; k += 2) acc += F[(size_t)list[k] * D + d];
  }
  red[t] = acc;
  __syncthreads();
  float anew = 0.0f;
  float fcnt = (float)total;
  if (t < 256) {
    acc = red[t] + red[t + 256];
    float ave = acc / fmaxf(fcnt, 1.0f);
    float denom = fcnt + Amount[c];
    float wgt = (denom > 0.0f) ? (fcnt / denom) : 0.0f;
    anew = Ave[c * D + d] * (1.0f - wgt) + ave * wgt;
  }
  __syncthreads();
  red[t] = (t < 256) ? anew * anew : 0.0f;
  __syncthreads();
  for (int st = 256; st > 0; st >>= 1) {
    if (t < st) red[t] += red[t + st];
    __syncthreads();
  }
  float R2 = red[0];
  float R = sqrtf(R2);
  float kap = 256.0f * R / (1.0f - R2);
  if (kap > 100000.0f || kap < 0.0f) kap = 100000.0f;
  if (t < 256) {
    float mu = anew / fmaxf(R, 1e-12f);
    unsigned short mb = f2bf(2.0f * kap * mu);
    int ch = (d >> 3) ^ (c & 7);  // 16B chunk swizzle
    Bg[c * 256 + ch * 8 + (d & 7)] = mb;
  }
  if (t == 0) {
    kap2[c] = kap * kap;
    float t2 = log2f(fmaxf(kap, 1e-10f));
    logc[c] = li0e_f(kap, t2) + lratio1<1>(kap) + kap - NUF * logf(kap + 1e-20f);
  }
}

// block = 16 rows x 128 classes, 512 threads (8 waves; wave w owns the
// 16-class strip [w*16, w*16+16)). s = kap2[c] + ||10f||^2 + bf16GEMM;
// logits via table; fused row softmax; per-block partial. Last-arriving
// block (write-through partials + relaxed agent counter, no L2 flush)
// does the fixed-order final reduction -> out. Bitwise deterministic.
__global__ __launch_bounds__(512) void k_dot(
    const float* __restrict__ F, const int* __restrict__ labels,
    const unsigned short* __restrict__ Bg, const float* __restrict__ kap2,
    const float* __restrict__ logc, const float* __restrict__ ltab,
    int N, int C, float* __restrict__ partials, unsigned* __restrict__ counter,
    float* __restrict__ out) {
  __shared__ __align__(16) char Bs[65536];  // B tile [128 n][256 k] bf16, swizzled
  __shared__ __align__(16) char As[8192];   // A tile [16 m][256 k] bf16, swizzled; tail scratch
  __shared__ float sf[16];
  __shared__ float redm[8][16];
  __shared__ float reds[8][16];
  __shared__ float rowpart[16];
  __shared__ int labs[16];
  __shared__ int lastflag;
  const int t = threadIdx.x;
  const int w = t >> 6, lane = t & 63;
  const int n0 = blockIdx.x * 16;

  // ---- B staging: 64 KB pre-swizzled bf16, global -> LDS async ----
  {
    const char* gsrc = (const char*)Bg + lane * 16;
    #pragma unroll
    for (int j = 0; j < 8; ++j) {
      int base = j * 8192 + w * 1024;
      __builtin_amdgcn_global_load_lds(
          (const __attribute__((address_space(1))) void*)(gsrc + base),
          (__attribute__((address_space(3))) void*)&Bs[base], 16, 0, 0);
    }
  }

  // ---- A staging: 16 rows of 10*F -> swizzled bf16 LDS; sf; labels ----
  {
    const int arow = t >> 5, acol = t & 31;  // 32 threads/row, 8 floats each
    const int n = n0 + arow;
    float v[8];
    if (n < N) {
      const float4* fp = (const float4*)(F + (size_t)n * D + acol * 8);
      float4 f0 = fp[0], f1 = fp[1];
      v[0] = f0.x * 10.f; v[1] = f0.y * 10.f; v[2] = f0.z * 10.f; v[3] = f0.w * 10.f;
      v[4] = f1.x * 10.f; v[5] = f1.y * 10.f; v[6] = f1.z * 10.f; v[7] = f1.w * 10.f;
    } else {
      #pragma unroll
      for (int e = 0; e < 8; ++e) v[e] = 0.0f;
    }
    float ps = 0.0f;
    #pragma unroll
    for (int e = 0; e < 8; ++e) ps = fmaf(v[e], v[e], ps);
    ps += __shfl_xor(ps, 1, 64); ps += __shfl_xor(ps, 2, 64);
    ps += __shfl_xor(ps, 4, 64); ps += __shfl_xor(ps, 8, 64);
    ps += __shfl_xor(ps, 16, 64);
    if ((lane & 31) == 0) sf[arow] = ps;
    bf16x8 pk;
    #pragma unroll
    for (int e = 0; e < 8; ++e) pk[e] = (short)f2bf(v[e]);
    int ch = acol ^ (arow & 7);
    *(bf16x8*)&As[arow * 512 + ch * 16] = pk;
    if (t < 16) {
      labs[t] = (n0 + t < N) ? labels[n0 + t] : -1;
      rowpart[t] = 0.0f;
    }
  }
  asm volatile("s_waitcnt vmcnt(0)" ::: "memory");
  __syncthreads();

  // ---- GEMM: wave w computes 16 rows x strip of 16 classes ----
  f32x4 acc = {0.f, 0.f, 0.f, 0.f};
  const int lrow = lane & 15, lk = lane >> 4;
  const int cls = w * 16 + lrow;
  #pragma unroll
  for (int s = 0; s < 8; ++s) {
    int kc = s * 4 + lk;
    bf16x8 a = *(const bf16x8*)&As[lrow * 512 + ((kc ^ (lrow & 7)) << 4)];
    bf16x8 b = *(const bf16x8*)&Bs[cls * 512 + ((kc ^ (cls & 7)) << 4)];
    acc = __builtin_amdgcn_mfma_f32_16x16x32_bf16(a, b, acc, 0, 0, 0);
  }

  // ---- logits: lane holds rows m = lk*4+r for class cls ----
  float kk = kap2[cls], lgc = logc[cls];
  float lg[4];
  #pragma unroll
  for (int r = 0; r < 4; ++r) {
    int m = lk * 4 + r;
    lg[r] = logit_from(acc[r] + kk + sf[m], ltab) - lgc;
  }
  if (cls >= C) {
    #pragma unroll
    for (int r = 0; r < 4; ++r) lg[r] = -INFINITY;
  }

  // ---- row max: 16-class shuffle within wave + LDS across 8 waves ----
  #pragma unroll
  for (int r = 0; r < 4; ++r) {
    float vmax = lg[r];
    vmax = fmaxf(vmax, __shfl_xor(vmax, 1, 64));
    vmax = fmaxf(vmax, __shfl_xor(vmax, 2, 64));
    vmax = fmaxf(vmax, __shfl_xor(vmax, 4, 64));
    vmax = fmaxf(vmax, __shfl_xor(vmax, 8, 64));
    if (lrow == 0) redm[w][lk * 4 + r] = vmax;
  }
  __syncthreads();
  float mrow[4];
  #pragma unroll
  for (int r = 0; r < 4; ++r) {
    int m = lk * 4 + r;
    float a0 = fmaxf(fmaxf(redm[0][m], redm[1][m]), fmaxf(redm[2][m], redm[3][m]));
    float a1 = fmaxf(fmaxf(redm[4][m], redm[5][m]), fmaxf(redm[6][m], redm[7][m]));
    mrow[r] = fmaxf(a0, a1);
    float e = expf(lg[r] - mrow[r]);
    e += __shfl_xor(e, 1, 64); e += __shfl_xor(e, 2, 64);
    e += __shfl_xor(e, 4, 64); e += __shfl_xor(e, 8, 64);
    if (lrow == 0) reds[w][m] = e;
  }
  __syncthreads();
  #pragma unroll
  for (int r = 0; r < 4; ++r) {
    int m = lk * 4 + r;
    float se = (reds[0][m] + reds[1][m]) + (reds[2][m] + reds[3][m]) +
               (reds[4][m] + reds[5][m]) + (reds[6][m] + reds[7][m]);
    float lse = mrow[r] + logf(se);
    if (cls == labs[m]) rowpart[m] = lse - lg[r];
  }
  __syncthreads();

  // ---- partial + fenceless completion protocol ----
  if (t == 0) {
    float a = 0.f;
    #pragma unroll
    for (int j = 0; j < 16; ++j) a += rowpart[j];
    // write-through (agent-scope) store: never dirty in local L2
    __hip_atomic_store(&partials[blockIdx.x], a, __ATOMIC_RELAXED,
                       __HIP_MEMORY_SCOPE_AGENT);
    // wait for OUR store to reach the coherence point (no cache flush)
    asm volatile("s_waitcnt vmcnt(0)" ::: "memory");
    unsigned old = __hip_atomic_fetch_add(counter, 1u, __ATOMIC_RELAXED,
                                          __HIP_MEMORY_SCOPE_AGENT);
    lastflag = (old == gridDim.x - 1) ? 1 : 0;
  }
  __syncthreads();

  if (lastflag) {  // last-arriving block: fixed-order final reduction
    const int nb = (int)gridDim.x;
    float* scratch = (float*)As;
    float a = 0.f;
    if (t < nb)
      a = __hip_atomic_load(&partials[t], __ATOMIC_RELAXED,
                            __HIP_MEMORY_SCOPE_AGENT);
    scratch[t] = a;
    __syncthreads();
    for (int st = 256; st > 0; st >>= 1) {
      if (t < st) scratch[t] += scratch[t + st];
      __syncthreads();
    }
    if (t == 0) out[0] = scratch[0] / (float)N;
  }
}

extern "C" void kernel_launch(void* const* d_in, const int* in_sizes, int n_in,
                              void* d_out, int out_size, void* d_ws, size_t ws_size,
                              hipStream_t stream) {
  const float* F = (const float*)d_in[0];
  const float* Ave = (const float*)d_in[1];
  const float* Amount = (const float*)d_in[2];
  const int* labels = (const int*)d_in[3];
  const int N = in_sizes[0] / D;
  const int C = in_sizes[2];

  unsigned short* Bg = (unsigned short*)d_ws;        // 65536 B: [128 n][256 k] bf16 swz
  float* kap2 = (float*)((char*)d_ws + 65536);       // 128
  float* logc = kap2 + C_MAX;                        // 128
  float* ltab = logc + C_MAX;                        // 16384
  float* partials = ltab + TN;                       // nb (<=512)
  unsigned* counter = (unsigned*)(partials + 512);

  k_prep<<<C + 32, 512, 0, stream>>>(F, Ave, Amount, labels, N, C, Bg, kap2,
                                     logc, ltab, counter);
  const int nb = (N + 15) / 16;
  k_dot<<<nb, 512, 0, stream>>>(F, labels, Bg, kap2, logc, ltab, N, C,
                                partials, counter, (float*)d_out);
}

// Round 8
// 27.382 us; speedup vs baseline: 1.0447x; 1.0447x over previous
//
#include <hip/hip_runtime.h>
#include <math.h>

#define D 256
#define NUF 127.0f
#define C_MAX 128
#define TN 16384
#define T0F (-4.0f)
#define T1F (16.75f)
#define DTF ((T1F - T0F) / (float)(TN - 1))
#define INVDTF ((float)(TN - 1) / (T1F - T0F))
#define LN2F 0.69314718056f
#define RSU 44.3614195558365f  // ln(2^64)

typedef __attribute__((ext_vector_type(8))) short bf16x8;
typedef __attribute__((ext_vector_type(4))) float f32x4;

// float -> bf16 bits, round-to-nearest-even
__device__ __forceinline__ unsigned short f2bf(float f) {
  unsigned u = __float_as_uint(f);
  u += 0x7FFFu + ((u >> 16) & 1u);
  return (unsigned short)(u >> 16);
}

// Miller downward recurrence (i = 254..1), linear space, 2^-64 rescale every
// P steps. Returns log(p_127/p_0) — identical truncation to the reference.
template<int P>
__device__ __forceinline__ float lratio1(float x) {
  float rx = 1.0f / fmaxf(x, 1e-10f);
  float a = 2.0f * rx;
  float cc = 508.0f * rx;  // 2i/x at i=254
  float p = 1.0f, q = 0.0f, k = 0.0f;
  #pragma unroll
  for (int s = 0; s < 127; ++s) {  // i = 254..128; last step yields p_127
    float tn = fmaf(cc, p, q);
    cc -= a; q = p; p = tn;
    if ((s % P) == P - 1 || s == 126) {
      bool b = p > 0x1p64f;
      float sc = b ? 0x1p-64f : 1.0f;
      p *= sc; q *= sc; k += b ? 1.0f : 0.0f;
    }
  }
  float pn = p, kn = k;
  #pragma unroll
  for (int s = 0; s < 127; ++s) {  // i = 127..1
    float tn = fmaf(cc, p, q);
    cc -= a; q = p; p = tn;
    if ((s % P) == P - 1) {
      bool b = p > 0x1p64f;
      float sc = b ? 0x1p-64f : 1.0f;
      p *= sc; q *= sc; k += b ? 1.0f : 0.0f;
    }
  }
  return logf(pn) - logf(p) + (kn - k) * RSU;
}

// log(i0e(x)) via A&S 9.8.1 / 9.8.2 (|err| < 2e-7); t2 = log2(x)
__device__ __forceinline__ float li0e_f(float x, float t2) {
  if (x >= 3.75f) {
    float t = 3.75f / x;
    float P = 0.39894228f + t*(0.01328592f + t*(0.00225319f + t*(-0.00157565f +
              t*(0.00916281f + t*(-0.02057706f + t*(0.02635537f + t*(-0.01647633f +
              t*0.00392377f)))))));
    return logf(P) - 0.5f * LN2F * t2;
  } else {
    float u = x * (1.0f / 3.75f); u *= u;
    float P = 1.0f + u*(3.5156229f + u*(3.0899424f + u*(1.2067492f +
              u*(0.2659732f + u*(0.0360768f + u*0.0045813f)))));
    return logf(P) - x;
  }
}

// logit (without -logc) from s = x^2, table-interpolated Bessel ratio
__device__ __forceinline__ float logit_from(float s, const float* __restrict__ ltab) {
  float x = sqrtf(fmaxf(s, 1e-20f));
  float t2 = log2f(x);
  float fi = fminf(fmaxf((t2 - T0F) * INVDTF, 0.0f), (float)(TN - 1) - 0.001f);
  int i0 = (int)fi;
  float fr = fi - (float)i0;
  float l0 = ltab[i0], l1 = ltab[i0 + 1];
  float lr = fmaf(l1 - l0, fr, l0);
  return li0e_f(x, t2) + lr + x - NUF * (LN2F * t2);
}

// blocks [0,C): per-class stats -> Bg (bf16(2*kappa*mu), [n][k] pre-swizzled),
//               kap2, logc. blocks [C, C+32): lr table; block C zero-pads.
__global__ __launch_bounds__(512) void k_prep(
    const float* __restrict__ F, const float* __restrict__ Ave,
    const float* __restrict__ Amount, const int* __restrict__ labels,
    int N, int C, unsigned short* __restrict__ Bg, float* __restrict__ kap2,
    float* __restrict__ logc, float* __restrict__ ltab) {
  const int t = threadIdx.x;
  const int bid = blockIdx.x;
  if (bid >= C) {
    int i = (bid - C) * 512 + t;
    if (i < TN) ltab[i] = lratio1<4>(exp2f(T0F + DTF * (float)i));
    if (bid == C && C < C_MAX) {
      uint4 z = make_uint4(0u, 0u, 0u, 0u);
      uint4* B4 = (uint4*)Bg;  // 32 uint4 per 512-byte class row
      for (int j = t; j < (C_MAX - C) * 32; j += 512) B4[C * 32 + j] = z;
      for (int j = t; j < C_MAX - C; j += 512) { kap2[C + j] = 0.0f; logc[C + j] = 0.0f; }
    }
    return;
  }
  const int c = bid;
  const int lane = t & 63, w = t >> 6;
  __shared__ int list[4096];
  __shared__ int wcnt[8];
  __shared__ float red[512];

  // parallel ballot-compaction of matching row indices (deterministic order)
  int total = 0;
  for (int base = 0; base < N; base += 512) {
    int row = base + t;
    bool m = (row < N) && (labels[row] == c);
    unsigned long long mask = __ballot(m);
    if (lane == 0) wcnt[w] = __popcll(mask);
    int before = __popcll(mask & ((1ULL << lane) - 1ULL));
    __syncthreads();
    int woff = total;
    #pragma unroll
    for (int i = 0; i < 8; ++i) { int v = wcnt[i]; if (i < w) woff += v; total += v; }
    if (m) list[woff + before] = row;
    __syncthreads();
  }

  // two halves accumulate alternating list entries; 8 loads in flight each
  const int d = t & 255, half = t >> 8;
  float acc = 0.0f;
  {
    int k = half;
    for (; k + 14 < total; k += 16) {
      int r0 = list[k],      r1 = list[k + 2],  r2 = list[k + 4],  r3 = list[k + 6];
      int r4 = list[k + 8],  r5 = list[k + 10], r6 = list[k + 12], r7 = list[k + 14];
      float v0 = F[(size_t)r0 * D + d], v1 = F[(size_t)r1 * D + d];
      float v2 = F[(size_t)r2 * D + d], v3 = F[(size_t)r3 * D + d];
      float v4 = F[(size_t)r4 * D + d], v5 = F[(size_t)r5 * D + d];
      float v6 = F[(size_t)r6 * D + d], v7 = F[(size_t)r7 * D + d];
      acc += v0; acc += v1; acc += v2; acc += v3;
      acc += v4; acc += v5; acc += v6; acc += v7;
    }
    for (; k < total; k += 2) acc += F[(size_t)list[k] * D + d];
  }
  red[t] = acc;
  __syncthreads();
  float anew = 0.0f;
  float fcnt = (float)total;
  if (t < 256) {
    acc = red[t] + red[t + 256];
    float ave = acc / fmaxf(fcnt, 1.0f);
    float denom = fcnt + Amount[c];
    float wgt = (denom > 0.0f) ? (fcnt / denom) : 0.0f;
    anew = Ave[c * D + d] * (1.0f - wgt) + ave * wgt;
  }
  __syncthreads();
  red[t] = (t < 256) ? anew * anew : 0.0f;
  __syncthreads();
  for (int st = 256; st > 0; st >>= 1) {
    if (t < st) red[t] += red[t + st];
    __syncthreads();
  }
  float R2 = red[0];
  float R = sqrtf(R2);
  float kap = 256.0f * R / (1.0f - R2);
  if (kap > 100000.0f || kap < 0.0f) kap = 100000.0f;
  if (t < 256) {
    float mu = anew / fmaxf(R, 1e-12f);
    unsigned short mb = f2bf(2.0f * kap * mu);
    // row c, k = d: 16B chunk index (d>>3) XOR-swizzled by (c&7)
    int ch = (d >> 3) ^ (c & 7);
    Bg[c * 256 + ch * 8 + (d & 7)] = mb;
  }
  if (t == 0) {
    kap2[c] = kap * kap;
    float t2 = log2f(fmaxf(kap, 1e-10f));
    logc[c] = li0e_f(kap, t2) + lratio1<1>(kap) + kap - NUF * logf(kap + 1e-20f);
  }
}

// block = 16 rows x 128 classes, 256 threads (4 waves).
// s = kap2[c] + ||10f||^2 + bf16GEMM(10f, 2*kappa*mu); logits via table;
// fused row softmax; per-block partial loss.
__global__ __launch_bounds__(256) void k_dot(
    const float* __restrict__ F, const int* __restrict__ labels,
    const unsigned short* __restrict__ Bg, const float* __restrict__ kap2,
    const float* __restrict__ logc, const float* __restrict__ ltab,
    int N, int C, float* __restrict__ partials) {
  __shared__ __align__(16) char Bs[65536];  // B tile [128 n][256 k] bf16, swizzled
  __shared__ __align__(16) char As[8192];   // A tile [16 m][256 k] bf16, swizzled
  __shared__ float sf[16];
  __shared__ float redm[4][16];
  __shared__ float reds[4][16];
  __shared__ float rowpart[16];
  __shared__ int labs[16];
  const int t = threadIdx.x;
  const int w = t >> 6, lane = t & 63;
  const int n0 = blockIdx.x * 16;

  // ---- B staging: 64 KB pre-swizzled bf16, global -> LDS async ----
  {
    const char* gsrc = (const char*)Bg + lane * 16;
    #pragma unroll
    for (int i = 0; i < 16; ++i) {
      int base = (w * 16 + i) * 1024;
      __builtin_amdgcn_global_load_lds(
          (const __attribute__((address_space(1))) void*)(gsrc + base),
          (__attribute__((address_space(3))) void*)&Bs[base], 16, 0, 0);
    }
  }

  // ---- A staging: 16 rows of 10*F -> swizzled bf16 LDS; sf; labels ----
  {
    const int arow = t >> 4, acol = t & 15;
    const int n = n0 + arow;
    float v[16];
    if (n < N) {
      const float4* fp = (const float4*)(F + (size_t)n * D + acol * 16);
      #pragma unroll
      for (int q = 0; q < 4; ++q) {
        float4 f4 = fp[q];
        v[q * 4 + 0] = f4.x * 10.f; v[q * 4 + 1] = f4.y * 10.f;
        v[q * 4 + 2] = f4.z * 10.f; v[q * 4 + 3] = f4.w * 10.f;
      }
    } else {
      #pragma unroll
      for (int e = 0; e < 16; ++e) v[e] = 0.0f;
    }
    float ps = 0.0f;
    #pragma unroll
    for (int e = 0; e < 16; ++e) ps = fmaf(v[e], v[e], ps);
    ps += __shfl_xor(ps, 1, 64); ps += __shfl_xor(ps, 2, 64);
    ps += __shfl_xor(ps, 4, 64); ps += __shfl_xor(ps, 8, 64);
    if (acol == 0) sf[arow] = ps;
    bf16x8 pk0, pk1;
    #pragma unroll
    for (int e = 0; e < 8; ++e) {
      pk0[e] = (short)f2bf(v[e]);
      pk1[e] = (short)f2bf(v[8 + e]);
    }
    int ch0 = (acol * 2) ^ (arow & 7);
    int ch1 = (acol * 2 + 1) ^ (arow & 7);
    *(bf16x8*)&As[arow * 512 + ch0 * 16] = pk0;
    *(bf16x8*)&As[arow * 512 + ch1 * 16] = pk1;
    if (t < 16) {
      labs[t] = (n0 + t < N) ? labels[n0 + t] : -1;
      rowpart[t] = 0.0f;
    }
  }
  asm volatile("s_waitcnt vmcnt(0)" ::: "memory");
  __syncthreads();

  // ---- GEMM: wave w owns n-tiles [w*32, w*32+16) and [w*32+16, w*32+32) ----
  f32x4 acc0 = {0.f, 0.f, 0.f, 0.f};
  f32x4 acc1 = {0.f, 0.f, 0.f, 0.f};
  const int lrow = lane & 15, lk = lane >> 4;
  const int nA = w * 32 + lrow, nB = nA + 16;
  #pragma unroll
  for (int s = 0; s < 8; ++s) {
    int kc = s * 4 + lk;
    bf16x8 a  = *(const bf16x8*)&As[lrow * 512 + ((kc ^ (lrow & 7)) << 4)];
    bf16x8 b0 = *(const bf16x8*)&Bs[nA * 512 + ((kc ^ (nA & 7)) << 4)];
    bf16x8 b1 = *(const bf16x8*)&Bs[nB * 512 + ((kc ^ (nB & 7)) << 4)];
    acc0 = __builtin_amdgcn_mfma_f32_16x16x32_bf16(a, b0, acc0, 0, 0, 0);
    acc1 = __builtin_amdgcn_mfma_f32_16x16x32_bf16(a, b1, acc1, 0, 0, 0);
  }

  // ---- logits: lane holds rows m = lk*4+r for classes nA, nB ----
  float kkA = kap2[nA], lgcA = logc[nA];
  float kkB = kap2[nB], lgcB = logc[nB];
  float lg0[4], lg1[4];
  #pragma unroll
  for (int r = 0; r < 4; ++r) {
    int m = lk * 4 + r;
    lg0[r] = logit_from(acc0[r] + kkA + sf[m], ltab) - lgcA;
    lg1[r] = logit_from(acc1[r] + kkB + sf[m], ltab) - lgcB;
  }
  if (nA >= C) {
    #pragma unroll
    for (int r = 0; r < 4; ++r) lg0[r] = -INFINITY;
  }
  if (nB >= C) {
    #pragma unroll
    for (int r = 0; r < 4; ++r) lg1[r] = -INFINITY;
  }

  // ---- row max: 16-lane shuffle (n within wave) + LDS (across waves) ----
  #pragma unroll
  for (int r = 0; r < 4; ++r) {
    float vmax = fmaxf(lg0[r], lg1[r]);
    vmax = fmaxf(vmax, __shfl_xor(vmax, 1, 64));
    vmax = fmaxf(vmax, __shfl_xor(vmax, 2, 64));
    vmax = fmaxf(vmax, __shfl_xor(vmax, 4, 64));
    vmax = fmaxf(vmax, __shfl_xor(vmax, 8, 64));
    if (lrow == 0) redm[w][lk * 4 + r] = vmax;
  }
  __syncthreads();
  float mrow[4];
  #pragma unroll
  for (int r = 0; r < 4; ++r) {
    int m = lk * 4 + r;
    mrow[r] = fmaxf(fmaxf(redm[0][m], redm[1][m]), fmaxf(redm[2][m], redm[3][m]));
    float e = expf(lg0[r] - mrow[r]) + expf(lg1[r] - mrow[r]);
    e += __shfl_xor(e, 1, 64); e += __shfl_xor(e, 2, 64);
    e += __shfl_xor(e, 4, 64); e += __shfl_xor(e, 8, 64);
    if (lrow == 0) reds[w][m] = e;
  }
  __syncthreads();
  #pragma unroll
  for (int r = 0; r < 4; ++r) {
    int m = lk * 4 + r;
    float lse = mrow[r] + logf(reds[0][m] + reds[1][m] + reds[2][m] + reds[3][m]);
    int lb = labs[m];
    if (nA == lb) rowpart[m] = lse - lg0[r];
    if (nB == lb) rowpart[m] = lse - lg1[r];
  }
  __syncthreads();
  if (t == 0) {
    float a = 0.f;
    #pragma unroll
    for (int j = 0; j < 16; ++j) a += rowpart[j];
    partials[blockIdx.x] = a;
  }
}

__global__ __launch_bounds__(256) void k_reduce(
    const float* __restrict__ partials, int nb, int N, float* __restrict__ out) {
  __shared__ float red[256];
  float s = 0.0f;
  for (int i = threadIdx.x; i < nb; i += 256) s += partials[i];
  red[threadIdx.x] = s;
  __syncthreads();
  for (int st = 128; st > 0; st >>= 1) {
    if (threadIdx.x < st) red[threadIdx.x] += red[threadIdx.x + st];
    __syncthreads();
  }
  if (threadIdx.x == 0) out[0] = red[0] / (float)N;
}

extern "C" void kernel_launch(void* const* d_in, const int* in_sizes, int n_in,
                              void* d_out, int out_size, void* d_ws, size_t ws_size,
                              hipStream_t stream) {
  const float* F = (const float*)d_in[0];
  const float* Ave = (const float*)d_in[1];
  const float* Amount = (const float*)d_in[2];
  const int* labels = (const int*)d_in[3];
  const int N = in_sizes[0] / D;
  const int C = in_sizes[2];

  unsigned short* Bg = (unsigned short*)d_ws;        // 65536 B: [128 n][256 k] bf16 swz
  float* kap2 = (float*)((char*)d_ws + 65536);       // 128
  float* logc = kap2 + C_MAX;                        // 128
  float* ltab = logc + C_MAX;                        // 16384
  float* partials = ltab + TN;                       // nb

  k_prep<<<C + 32, 512, 0, stream>>>(F, Ave, Amount, labels, N, C, Bg, kap2,
                                     logc, ltab);
  const int nb = (N + 15) / 16;
  k_dot<<<nb, 256, 0, stream>>>(F, labels, Bg, kap2, logc, ltab, N, C, partials);
  k_reduce<<<1, 256, 0, stream>>>(partials, nb, N, (float*)d_out);
}